// Round 3
// baseline (888426.465 us; speedup 1.0000x reference)
//
#include <hip/hip_runtime.h>
#include <stdint.h>

typedef unsigned int  u32;
typedef unsigned short u16;

#define SEQ    8192
#define HID    1024
#define NL     5
#define NWG    256
#define TPB    256
#define PAIRS  20                 // (layer,unit) pairs per WG; NWG*PAIRS = NL*HID
#define RPW    20                 // gate-rows per wave (4 waves * 20 = 80 = PAIRS*4)
#define WSTEPS (SEQ + NL - 1)     // 8196 wavefront steps

// ---- workspace layout (bytes) ----
#define WS_X0    ((size_t)0)                        // 8192*512 u32 = 16 MiB (bf16 packed)
#define WS_H5    ((size_t)16*1024*1024)             // 16 MiB
#define WS_SLOT  ((size_t)32*1024*1024)             // 5*2*512 u32 = 20 KiB (pad 32 KiB)
#define WS_CNT   (WS_SLOT + (size_t)32*1024)        // barrier counter
#define WS_FLAG  (WS_CNT + 128)                     // dtype flag: 1 = f32 inputs, 0 = bf16
#define WS_NEED  (WS_CNT + 256)

// ---------------- helpers ----------------
__device__ __forceinline__ float bf2f(u16 v) {
  return __uint_as_float(((u32)v) << 16);
}
// exact bf16->f32 unpack of a packed pair: low = bits<<16, high = bits&0xffff0000
__device__ __forceinline__ float bflo(u32 v) { return __uint_as_float(v << 16); }
__device__ __forceinline__ float bfhi(u32 v) { return __uint_as_float(v & 0xffff0000u); }

__device__ __forceinline__ u16 f2bf(float f) {            // round-to-nearest-even
  u32 u = __float_as_uint(f);
  u32 r = u + 0x7fffu + ((u >> 16) & 1u);
  return (u16)(r >> 16);
}
__device__ __forceinline__ float lrelu(float x) { return (x >= 0.f) ? x : 0.01f * x; }
__device__ __forceinline__ float sigm(float x)  { return 1.f / (1.f + __expf(-x)); }
__device__ __forceinline__ float tanh_f(float x) {
  float e = __expf(-2.f * fabsf(x));
  float t = (1.f - e) / (1.f + e);
  return (x >= 0.f) ? t : -t;
}

__device__ __forceinline__ u32 agent_load(const u32* p) {
  return __hip_atomic_load((u32*)p, __ATOMIC_RELAXED, __HIP_MEMORY_SCOPE_AGENT);
}
__device__ __forceinline__ void agent_store(u32* p, u32 v) {
  __hip_atomic_store(p, v, __ATOMIC_RELAXED, __HIP_MEMORY_SCOPE_AGENT);
}

// grid barrier: monotonic counter, sense-free. All WGs guaranteed co-resident
// (VGPR usage > 256/thread forces exactly 1 block/CU; grid == 256 == #CUs).
__device__ __forceinline__ void gbar(u32* counter, u32 target, int& budget) {
  __threadfence();            // release our slot stores (agent scope, cross-XCD)
  __syncthreads();
  if (threadIdx.x == 0) {
    __hip_atomic_fetch_add(counter, 1u, __ATOMIC_RELEASE, __HIP_MEMORY_SCOPE_AGENT);
    while (__hip_atomic_load(counter, __ATOMIC_ACQUIRE, __HIP_MEMORY_SCOPE_AGENT) < target) {
      __builtin_amdgcn_s_sleep(2);
      if (--budget < 0) break;  // bounded: never hard-hang the harness
    }
  }
  __syncthreads();
  __threadfence();            // acquire side
}

// ---------------- K0: dtype probe ----------------
// f32 weights ~N(0,1/8): f32 exponent field of nearly every word is in [100,140].
// packed-bf16 words: that field is (exp lsb || mantissa bits) -> ~16% in range.
__global__ void k_detect(const u32* __restrict__ w1, u32* __restrict__ flag) {
  int lane = threadIdx.x;       // 64 threads
  int cnt = 0;
#pragma unroll
  for (int i = 0; i < 4; ++i) {
    u32 w = w1[lane * 4 + i];
    u32 e = (w >> 23) & 0xffu;
    cnt += (e >= 100u && e <= 140u) ? 1 : 0;
  }
  cnt += __shfl_xor(cnt, 32);
  cnt += __shfl_xor(cnt, 16);
  cnt += __shfl_xor(cnt, 8);
  cnt += __shfl_xor(cnt, 4);
  cnt += __shfl_xor(cnt, 2);
  cnt += __shfl_xor(cnt, 1);
  if (lane == 0) *flag = (cnt > 128) ? 1u : 0u;
}

// ---------------- K1: X0 = leaky_relu(data_in @ w1.T + b1), stored packed bf16 ----------------
__global__ void __launch_bounds__(256) k_in(const void* __restrict__ din,
                                            const void* __restrict__ w1,
                                            const void* __restrict__ b1,
                                            u32* __restrict__ X0,
                                            const u32* __restrict__ flagp) {
  const u32 isf = *flagp;
  int t = blockIdx.x, tid = threadIdx.x;
  __shared__ float xs[64];                     // canonical f32 inputs of row t
  if (isf) {
    if (tid < 64) xs[tid] = ((const float*)din)[(size_t)t * 64 + tid];
  } else {
    if (tid < 32) {
      u32 v = ((const u32*)din)[(size_t)t * 32 + tid];
      xs[2 * tid]     = bflo(v);
      xs[2 * tid + 1] = bfhi(v);
    }
  }
  __syncthreads();
  float o[4];
#pragma unroll
  for (int r = 0; r < 4; ++r) {
    int i = tid * 4 + r;
    float a = 0.f;
    if (isf) {
      const float* wr = (const float*)w1 + (size_t)i * 64;
#pragma unroll
      for (int d = 0; d < 64; ++d) a = fmaf(wr[d], xs[d], a);
      a += ((const float*)b1)[i];
    } else {
      const u32* wr = (const u32*)w1 + (size_t)i * 32;
#pragma unroll
      for (int d = 0; d < 32; ++d) {
        u32 w = wr[d];
        a = fmaf(bflo(w), xs[2 * d], a);
        a = fmaf(bfhi(w), xs[2 * d + 1], a);
      }
      a += bf2f(((const u16*)b1)[i]);
    }
    o[r] = lrelu(a);
  }
  X0[(size_t)t * 512 + tid * 2]     = (u32)f2bf(o[0]) | ((u32)f2bf(o[1]) << 16);
  X0[(size_t)t * 512 + tid * 2 + 1] = (u32)f2bf(o[2]) | ((u32)f2bf(o[3]) << 16);
}

// ---------------- K2: persistent wavefront LSTM ----------------
// WG wg owns 20 flattened (layer,unit) pairs g = wg*20 .. wg*20+19, l = g>>10, j = g&1023.
// Row dot = [Wih_row || Whh_row] (2048 elems) . [x || h]; lane covers 32 elems (lane<32 -> Wih/x half).
__global__ void __launch_bounds__(TPB, 1) k_wave(const void* __restrict__ WihP,
                                                 const void* __restrict__ WhhP,
                                                 const void* __restrict__ bihP,
                                                 const void* __restrict__ bhhP,
                                                 const void* __restrict__ h0P,
                                                 const void* __restrict__ c0P,
                                                 const u32* __restrict__ X0,
                                                 u32* __restrict__ H5,
                                                 u32* slots, u32* counter,
                                                 const u32* __restrict__ flagp) {
  const u32 isf = *flagp;
  const int tid  = threadIdx.x;
  const int lane = tid & 63;
  const int wv   = tid >> 6;
  const int wg   = blockIdx.x;

  __shared__ u32   vlds[2][64 * 20];  // [layer-sel][lane*20 + d]  (pad 20 kills bank conflicts)
  __shared__ float zrow[80];
  __shared__ float bias[80];
  __shared__ float clds[PAIRS];
  __shared__ u16   hlds[PAIRS];

  // ---- load weights to registers (320 VGPRs/lane), packed bf16 canonical ----
  u32 W[RPW][16];
  if (isf) {
    const float* matf = (lane < 32) ? (const float*)WihP : (const float*)WhhP;
#pragma unroll
    for (int i = 0; i < RPW; ++i) {
      int rr = wv * RPW + i;
      int p = rr >> 2, q = rr & 3;
      int g = wg * PAIRS + p;
      int lg = g >> 10, j = g & 1023;
      const float4* s4 = (const float4*)(matf + ((size_t)(lg * 4096 + q * 1024 + j)) * 1024 + (lane & 31) * 32);
#pragma unroll
      for (int q4 = 0; q4 < 8; ++q4) {
        float4 f = s4[q4];
        W[i][q4 * 2]     = (u32)f2bf(f.x) | ((u32)f2bf(f.y) << 16);
        W[i][q4 * 2 + 1] = (u32)f2bf(f.z) | ((u32)f2bf(f.w) << 16);
      }
    }
  } else {
    const u32* mat = (lane < 32) ? (const u32*)WihP : (const u32*)WhhP;
#pragma unroll
    for (int i = 0; i < RPW; ++i) {
      int rr = wv * RPW + i;
      int p = rr >> 2, q = rr & 3;
      int g = wg * PAIRS + p;
      int lg = g >> 10, j = g & 1023;
      const uint4* s4 = (const uint4*)(mat + ((size_t)(lg * 4096 + q * 1024 + j)) * 512 + (lane & 31) * 16);
      uint4 a0 = s4[0], a1 = s4[1], a2 = s4[2], a3 = s4[3];
      W[i][0]=a0.x; W[i][1]=a0.y; W[i][2]=a0.z;  W[i][3]=a0.w;
      W[i][4]=a1.x; W[i][5]=a1.y; W[i][6]=a1.z;  W[i][7]=a1.w;
      W[i][8]=a2.x; W[i][9]=a2.y; W[i][10]=a2.z; W[i][11]=a2.w;
      W[i][12]=a3.x;W[i][13]=a3.y;W[i][14]=a3.z; W[i][15]=a3.w;
    }
  }

  if (tid < 80) {
    int p = tid >> 2, q = tid & 3;
    int g = wg * PAIRS + p, lg = g >> 10, j = g & 1023;
    int r = lg * 4096 + q * 1024 + j;
    bias[tid] = isf ? (((const float*)bihP)[r] + ((const float*)bhhP)[r])
                    : (bf2f(((const u16*)bihP)[r]) + bf2f(((const u16*)bhhP)[r]));
  }
  if (tid < PAIRS) {
    int g = wg * PAIRS + tid, lg = g >> 10, j = g & 1023;
    clds[tid] = isf ? ((const float*)c0P)[lg * 1024 + j] : bf2f(((const u16*)c0P)[lg * 1024 + j]);
  }
  if (tid < PAIRS / 2) {          // publish h0 into BOTH parity slots (pairs never straddle layers)
    int g = wg * PAIRS + 2 * tid, lg = g >> 10, j = g & 1023;
    u32 v;
    if (isf) {
      const float* h0f = (const float*)h0P;
      v = (u32)f2bf(h0f[lg * 1024 + j]) | ((u32)f2bf(h0f[lg * 1024 + j + 1]) << 16);
    } else {
      const u16* h0b = (const u16*)h0P;
      v = (u32)h0b[lg * 1024 + j] | ((u32)h0b[lg * 1024 + j + 1] << 16);
    }
    agent_store(&slots[(size_t)(lg * 2 + 0) * 512 + (j >> 1)], v);
    agent_store(&slots[(size_t)(lg * 2 + 1) * 512 + (j >> 1)], v);
  }

  int budget = 20000000;
  gbar(counter, NWG, budget);

  const int l_lo = (wg * PAIRS) >> 10;
  const int l_hi = (wg * PAIRS + PAIRS - 1) >> 10;

  for (int s = 0; s < WSTEPS; ++s) {
    // ---- stage v = [x || h] for each layer this WG touches ----
#pragma unroll
    for (int sel = 0; sel < 2; ++sel) {
      int L = l_lo + sel;
      if (L <= l_hi) {
        int t = s - L;
        if (t >= 0 && t < SEQ) {
          const u32* hsrc = slots + (size_t)(L * 2 + ((t + 1) & 1)) * 512;        // h_{L,t-1}
          const u32* xsrc = (L == 0) ? (X0 + (size_t)t * 512)
                                     : (slots + (size_t)((L - 1) * 2 + (t & 1)) * 512);  // h_{L-1,t}
#pragma unroll
          for (int rr2 = 0; rr2 < 4; ++rr2) {
            int gidx = tid + rr2 * 256;          // u32 index 0..1023 (bf16 pair index)
            u32 val;
            if (gidx < 512) val = (L == 0) ? xsrc[gidx] : agent_load(&xsrc[gidx]);
            else            val = agent_load(&hsrc[gidx - 512]);
            vlds[sel][(gidx >> 4) * 20 + (gidx & 15)] = val;
          }
        }
      }
    }
    __syncthreads();

    // ---- 20 row dots per wave ----
    {
      int curl = -1;
      float vf[32];                 // v-fragment unpacked to f32 once per layer-switch
#pragma unroll
      for (int i = 0; i < RPW; ++i) {
        int rr = wv * RPW + i;
        int p = rr >> 2;
        int g = wg * PAIRS + p;
        int lg = g >> 10;
        int t = s - lg;
        if (t >= 0 && t < SEQ) {
          if (lg != curl) {
            curl = lg;
            const u32* vb = &vlds[lg - l_lo][lane * 20];
#pragma unroll
            for (int d = 0; d < 16; ++d) {
              u32 x = vb[d];
              vf[2 * d]     = bflo(x);
              vf[2 * d + 1] = bfhi(x);
            }
          }
          float a0 = 0.f, a1 = 0.f, a2 = 0.f, a3 = 0.f;
#pragma unroll
          for (int d = 0; d < 16; d += 4) {
            a0 = fmaf(bflo(W[i][d]),     vf[2*d],     a0);
            a0 = fmaf(bfhi(W[i][d]),     vf[2*d+1],   a0);
            a1 = fmaf(bflo(W[i][d+1]),   vf[2*d+2],   a1);
            a1 = fmaf(bfhi(W[i][d+1]),   vf[2*d+3],   a1);
            a2 = fmaf(bflo(W[i][d+2]),   vf[2*d+4],   a2);
            a2 = fmaf(bfhi(W[i][d+2]),   vf[2*d+5],   a2);
            a3 = fmaf(bflo(W[i][d+3]),   vf[2*d+6],   a3);
            a3 = fmaf(bfhi(W[i][d+3]),   vf[2*d+7],   a3);
          }
          float r = (a0 + a1) + (a2 + a3);
          r += __shfl_xor(r, 32);
          r += __shfl_xor(r, 16);
          r += __shfl_xor(r, 8);
          r += __shfl_xor(r, 4);
          r += __shfl_xor(r, 2);
          r += __shfl_xor(r, 1);
          if (lane == 0) zrow[rr] = r;
        }
      }
    }
    __syncthreads();

    // ---- gates + cell update (one thread per owned unit) ----
    if (tid < PAIRS) {
      int g = wg * PAIRS + tid, lg = g >> 10;
      int t = s - lg;
      if (t >= 0 && t < SEQ) {
        float zi = zrow[tid * 4 + 0] + bias[tid * 4 + 0];
        float zf = zrow[tid * 4 + 1] + bias[tid * 4 + 1];
        float zg = zrow[tid * 4 + 2] + bias[tid * 4 + 2];
        float zo = zrow[tid * 4 + 3] + bias[tid * 4 + 3];
        float ig = sigm(zi), fg = sigm(zf), gg = tanh_f(zg), og = sigm(zo);
        float c = fg * clds[tid] + ig * gg;
        clds[tid] = c;
        hlds[tid] = f2bf(og * tanh_f(c));
      }
    }
    __syncthreads();

    // ---- publish h (packed pairs) ----
    if (tid < PAIRS / 2) {
      int g = wg * PAIRS + 2 * tid, lg = g >> 10, j = g & 1023;
      int t = s - lg;
      if (t >= 0 && t < SEQ) {
        u32 v = (u32)hlds[2 * tid] | ((u32)hlds[2 * tid + 1] << 16);
        agent_store(&slots[(size_t)(lg * 2 + (t & 1)) * 512 + (j >> 1)], v);
        if (lg == NL - 1) H5[(size_t)t * 512 + (j >> 1)] = v;
      }
    }

    gbar(counter, (u32)NWG * (u32)(s + 2), budget);
  }
}

// ---------------- K3: out = tanh(leaky_relu(h5) @ w2.T + b2) ----------------
__global__ void __launch_bounds__(256) k_out(const u32* __restrict__ H5,
                                             const void* __restrict__ w2,
                                             const void* __restrict__ b2,
                                             void* __restrict__ out,
                                             const u32* __restrict__ flagp) {
  const u32 isf = *flagp;
  int t = blockIdx.x, tid = threadIdx.x;
  __shared__ float hs[1024];
  __shared__ float part[256];
#pragma unroll
  for (int r = 0; r < 2; ++r) {
    int idx = tid + r * 256;
    u32 v = H5[(size_t)t * 512 + idx];
    hs[2 * idx]     = lrelu(bflo(v));
    hs[2 * idx + 1] = lrelu(bfhi(v));
  }
  __syncthreads();
  int n = tid & 63, qq = tid >> 6;
  float a = 0.f;
  if (isf) {
    const float* wr = (const float*)w2 + (size_t)n * 1024 + qq * 256;
    const float* hb = &hs[qq * 256];
#pragma unroll
    for (int d = 0; d < 256; ++d) a = fmaf(wr[d], hb[d], a);
  } else {
    const u32* wr = (const u32*)w2 + (size_t)n * 512 + qq * 128;
    const float* hb = &hs[qq * 256];
#pragma unroll
    for (int d = 0; d < 128; ++d) {
      u32 w = wr[d];
      a = fmaf(bflo(w), hb[2 * d], a);
      a = fmaf(bfhi(w), hb[2 * d + 1], a);
    }
  }
  part[tid] = a;
  __syncthreads();
  if (tid < 64) {
    float bb = isf ? ((const float*)b2)[tid] : bf2f(((const u16*)b2)[tid]);
    float y = part[tid] + part[tid + 64] + part[tid + 128] + part[tid + 192] + bb;
    float r = tanh_f(y);
    if (isf) ((float*)out)[(size_t)t * 64 + tid] = r;
    else     ((u16*)out)[(size_t)t * 64 + tid] = f2bf(r);
  }
}

// ---------------- launcher ----------------
extern "C" void kernel_launch(void* const* d_in, const int* in_sizes, int n_in,
                              void* d_out, int out_size, void* d_ws, size_t ws_size,
                              hipStream_t stream) {
  (void)in_sizes; (void)n_in; (void)out_size;
  if (ws_size < WS_NEED) return;   // fail visibly rather than corrupt

  const void* din = d_in[0];
  const void* w1  = d_in[1];
  const void* b1  = d_in[2];
  const void* Wih = d_in[3];
  const void* Whh = d_in[4];
  const void* bih = d_in[5];
  const void* bhh = d_in[6];
  const void* w2  = d_in[7];
  const void* b2  = d_in[8];
  const void* h0  = d_in[9];
  const void* c0  = d_in[10];

  char* ws = (char*)d_ws;
  u32* X0   = (u32*)(ws + WS_X0);
  u32* H5   = (u32*)(ws + WS_H5);
  u32* slot = (u32*)(ws + WS_SLOT);
  u32* cnt  = (u32*)(ws + WS_CNT);
  u32* flag = (u32*)(ws + WS_FLAG);

  hipMemsetAsync(cnt, 0, 256, stream);                       // ws is poisoned 0xAA each run
  k_detect<<<1, 64, 0, stream>>>((const u32*)w1, flag);
  k_in  <<<SEQ, 256, 0, stream>>>(din, w1, b1, X0, flag);
  k_wave<<<NWG, TPB, 0, stream>>>(Wih, Whh, bih, bhh, h0, c0, X0, H5, slot, cnt, flag);
  k_out <<<SEQ, 256, 0, stream>>>(H5, w2, b2, d_out, flag);
}

// Round 4
// 251694.019 us; speedup vs baseline: 3.5298x; 3.5298x over previous
//
#include <hip/hip_runtime.h>
#include <stdint.h>

typedef unsigned int  u32;
typedef unsigned short u16;

#define SEQ    8192
#define HID    1024
#define NL     5
#define NWG    256
#define TPB    256
#define PAIRS  20                 // (layer,unit) pairs per WG; NWG*PAIRS = NL*HID
#define RPW    20                 // gate-rows per wave (4 waves * 20 = 80 = PAIRS*4)
#define NVR    12                 // rows kept in VGPRs per wave
#define NLR    8                  // rows kept in LDS per wave (NVR+NLR == RPW)
#define WSTEPS (SEQ + NL - 1)     // 8196 wavefront steps
#define LWGS   52                 // producer WGs per layer (52 each, boundaries shared)

// ---- workspace layout (bytes) ----
#define WS_X0    ((size_t)0)                        // 8192*512 u32 = 16 MiB (bf16 packed)
#define WS_H5    ((size_t)16*1024*1024)             // 16 MiB
#define WS_SLOT  ((size_t)32*1024*1024)             // 5*2*512 u32 = 20 KiB (pad 32 KiB)
#define WS_SYNC  (WS_SLOT + (size_t)32*1024)        // flags[5][64] u32 + dtype flag @+2048
#define WS_NEED  (WS_SYNC + 4096)

// ---------------- helpers ----------------
__device__ __forceinline__ float bf2f(u16 v) { return __uint_as_float(((u32)v) << 16); }
__device__ __forceinline__ float bflo(u32 v) { return __uint_as_float(v << 16); }
__device__ __forceinline__ float bfhi(u32 v) { return __uint_as_float(v & 0xffff0000u); }

__device__ __forceinline__ u16 f2bf(float f) {            // round-to-nearest-even
  u32 u = __float_as_uint(f);
  u32 r = u + 0x7fffu + ((u >> 16) & 1u);
  return (u16)(r >> 16);
}
__device__ __forceinline__ float lrelu(float x) { return (x >= 0.f) ? x : 0.01f * x; }
__device__ __forceinline__ float sigm(float x)  { return 1.f / (1.f + __expf(-x)); }
__device__ __forceinline__ float tanh_f(float x) {
  float e = __expf(-2.f * fabsf(x));
  float t = (1.f - e) / (1.f + e);
  return (x >= 0.f) ? t : -t;
}

__device__ __forceinline__ u32 agent_load(const u32* p) {
  return __hip_atomic_load((u32*)p, __ATOMIC_RELAXED, __HIP_MEMORY_SCOPE_AGENT);
}
__device__ __forceinline__ void agent_store(u32* p, u32 v) {
  __hip_atomic_store(p, v, __ATOMIC_RELAXED, __HIP_MEMORY_SCOPE_AGENT);
}

__device__ __forceinline__ int first_wg(int l) { return (l << 10) / PAIRS; }  // {0,51,102,153,204}

// ---------------- K0: dtype probe ----------------
// f32 weights ~N(0,1/8): f32 exponent field of nearly every word in [100,140].
// packed-bf16 words: that field is (exp lsb || mantissa) -> ~16% in range.
__global__ void k_detect(const u32* __restrict__ w1, u32* __restrict__ flag) {
  int lane = threadIdx.x;       // 64 threads
  int cnt = 0;
#pragma unroll
  for (int i = 0; i < 4; ++i) {
    u32 w = w1[lane * 4 + i];
    u32 e = (w >> 23) & 0xffu;
    cnt += (e >= 100u && e <= 140u) ? 1 : 0;
  }
  cnt += __shfl_xor(cnt, 32); cnt += __shfl_xor(cnt, 16); cnt += __shfl_xor(cnt, 8);
  cnt += __shfl_xor(cnt, 4);  cnt += __shfl_xor(cnt, 2);  cnt += __shfl_xor(cnt, 1);
  if (lane == 0) *flag = (cnt > 128) ? 1u : 0u;
}

// ---------------- K1: X0 = leaky_relu(data_in @ w1.T + b1), stored packed bf16 ----------------
__global__ void __launch_bounds__(256) k_in(const void* __restrict__ din,
                                            const void* __restrict__ w1,
                                            const void* __restrict__ b1,
                                            u32* __restrict__ X0,
                                            const u32* __restrict__ flagp) {
  const u32 isf = *flagp;
  int t = blockIdx.x, tid = threadIdx.x;
  __shared__ float xs[64];
  if (isf) {
    if (tid < 64) xs[tid] = ((const float*)din)[(size_t)t * 64 + tid];
  } else {
    if (tid < 32) {
      u32 v = ((const u32*)din)[(size_t)t * 32 + tid];
      xs[2 * tid] = bflo(v); xs[2 * tid + 1] = bfhi(v);
    }
  }
  __syncthreads();
  float o[4];
#pragma unroll
  for (int r = 0; r < 4; ++r) {
    int i = tid * 4 + r;
    float a = 0.f;
    if (isf) {
      const float* wr = (const float*)w1 + (size_t)i * 64;
#pragma unroll
      for (int d = 0; d < 64; ++d) a = fmaf(wr[d], xs[d], a);
      a += ((const float*)b1)[i];
    } else {
      const u32* wr = (const u32*)w1 + (size_t)i * 32;
#pragma unroll
      for (int d = 0; d < 32; ++d) {
        u32 w = wr[d];
        a = fmaf(bflo(w), xs[2 * d], a);
        a = fmaf(bfhi(w), xs[2 * d + 1], a);
      }
      a += bf2f(((const u16*)b1)[i]);
    }
    o[r] = lrelu(a);
  }
  X0[(size_t)t * 512 + tid * 2]     = (u32)f2bf(o[0]) | ((u32)f2bf(o[1]) << 16);
  X0[(size_t)t * 512 + tid * 2 + 1] = (u32)f2bf(o[2]) | ((u32)f2bf(o[3]) << 16);
}

// ---------------- K2: persistent wavefront LSTM ----------------
// WG wg owns 20 flattened (layer,unit) pairs g = wg*20+p, l=g>>10, j=g&1023.
// Row dot = [Wih_row || Whh_row] (2048 elems) . [x || h]; lane covers 32 elems.
// Weights: 12 rows/wave in VGPRs + 8 rows/wave in LDS (lane-major, conflict-free).
// Sync: per-layer flag arrays (one word per producer WG, no RMW). Before step s,
// a WG waits until flags of layers [l_lo-1 .. l_hi+1] are all >= s+1 (init == 1,
// step s completion == s+2). This covers input availability, own recurrence, and
// WAR on the parity slot.
__global__ void __launch_bounds__(TPB, 1) k_wave(const void* __restrict__ WihP,
                                                 const void* __restrict__ WhhP,
                                                 const void* __restrict__ bihP,
                                                 const void* __restrict__ bhhP,
                                                 const void* __restrict__ h0P,
                                                 const void* __restrict__ c0P,
                                                 const u32* __restrict__ X0,
                                                 u32* __restrict__ H5,
                                                 u32* slots, u32* flags,
                                                 const u32* __restrict__ flagp) {
  const u32 isf = *flagp;
  const int tid  = threadIdx.x;
  const int lane = tid & 63;
  const int wv   = tid >> 6;
  const int wg   = blockIdx.x;

  __shared__ u32   vlds[2][64 * 20];            // [layer-sel][lane*20 + d] (pad 20)
  __shared__ u32   wlds[4 * NLR * 16 * 64];     // [wave][ldsrow][d][lane] 128 KiB
  __shared__ float zrow[80];

  // ---- load weights: rows 0..NVR-1 -> VGPRs, rows NVR..19 -> LDS ----
  u32 W[NVR][16];
#pragma unroll
  for (int i = 0; i < RPW; ++i) {
    int rr = wv * RPW + i;
    int p = rr >> 2, q = rr & 3;
    int g = wg * PAIRS + p;
    int lg = g >> 10, j = g & 1023;
    u32 tmp[16];
    if (isf) {
      const float* matf = (lane < 32) ? (const float*)WihP : (const float*)WhhP;
      const float4* s4 = (const float4*)(matf + ((size_t)(lg * 4096 + q * 1024 + j)) * 1024 + (lane & 31) * 32);
#pragma unroll
      for (int q4 = 0; q4 < 8; ++q4) {
        float4 f = s4[q4];
        tmp[q4 * 2]     = (u32)f2bf(f.x) | ((u32)f2bf(f.y) << 16);
        tmp[q4 * 2 + 1] = (u32)f2bf(f.z) | ((u32)f2bf(f.w) << 16);
      }
    } else {
      const u32* mat = (lane < 32) ? (const u32*)WihP : (const u32*)WhhP;
      const uint4* s4 = (const uint4*)(mat + ((size_t)(lg * 4096 + q * 1024 + j)) * 512 + (lane & 31) * 16);
      uint4 a0 = s4[0], a1 = s4[1], a2 = s4[2], a3 = s4[3];
      tmp[0]=a0.x; tmp[1]=a0.y; tmp[2]=a0.z;  tmp[3]=a0.w;
      tmp[4]=a1.x; tmp[5]=a1.y; tmp[6]=a1.z;  tmp[7]=a1.w;
      tmp[8]=a2.x; tmp[9]=a2.y; tmp[10]=a2.z; tmp[11]=a2.w;
      tmp[12]=a3.x;tmp[13]=a3.y;tmp[14]=a3.z; tmp[15]=a3.w;
    }
    if (i < NVR) {
#pragma unroll
      for (int d = 0; d < 16; ++d) W[i][d] = tmp[d];
    } else {
      u32* wl = &wlds[(((wv * NLR) + (i - NVR)) * 16) * 64 + lane];
#pragma unroll
      for (int d = 0; d < 16; ++d) wl[d * 64] = tmp[d];
    }
  }

  // ---- per-unit state in wave0 registers (lane < PAIRS owns one unit) ----
  float cst = 0.f;        // cell state
  float b0 = 0.f, b1g = 0.f, b2g = 0.f, b3g = 0.f;  // 4 gate biases
  if (wv == 0 && lane < PAIRS) {
    int g = wg * PAIRS + lane, lg = g >> 10, j = g & 1023;
    cst = isf ? ((const float*)c0P)[lg * 1024 + j] : bf2f(((const u16*)c0P)[lg * 1024 + j]);
#pragma unroll
    for (int q = 0; q < 4; ++q) {
      int r = lg * 4096 + q * 1024 + j;
      float bb = isf ? (((const float*)bihP)[r] + ((const float*)bhhP)[r])
                     : (bf2f(((const u16*)bihP)[r]) + bf2f(((const u16*)bhhP)[r]));
      if (q == 0) b0 = bb; else if (q == 1) b1g = bb; else if (q == 2) b2g = bb; else b3g = bb;
    }
  }
  if (tid < PAIRS / 2) {          // publish h0 into BOTH parity slots
    int g = wg * PAIRS + 2 * tid, lg = g >> 10, j = g & 1023;
    u32 v;
    if (isf) {
      const float* h0f = (const float*)h0P;
      v = (u32)f2bf(h0f[lg * 1024 + j]) | ((u32)f2bf(h0f[lg * 1024 + j + 1]) << 16);
    } else {
      const u16* h0b = (const u16*)h0P;
      v = (u32)h0b[lg * 1024 + j] | ((u32)h0b[lg * 1024 + j + 1] << 16);
    }
    agent_store(&slots[(size_t)(lg * 2 + 0) * 512 + (j >> 1)], v);
    agent_store(&slots[(size_t)(lg * 2 + 1) * 512 + (j >> 1)], v);
  }

  const int l_lo = (wg * PAIRS) >> 10;
  const int l_hi = (wg * PAIRS + PAIRS - 1) >> 10;
  const int mlo = (l_lo > 0) ? l_lo - 1 : 0;
  const int mhi = (l_hi < NL - 1) ? l_hi + 1 : NL - 1;
  const int f_lo = first_wg(l_lo), f_hi = first_wg(l_hi);

  __threadfence();
  __syncthreads();
  if (tid == 0) {                               // init done: flag = 1
    agent_store(&flags[l_lo * 64 + (wg - f_lo)], 1u);
    if (l_hi != l_lo) agent_store(&flags[l_hi * 64 + (wg - f_hi)], 1u);
  }

  int budget = 4000000;                         // bounded polling: never hard-hang

  for (int s = 0; s < WSTEPS; ++s) {
    // ---- wait: neighbor layers finished step s-1 (flag >= s+1) ----
    if (wv == 0) {
      u32 need = (u32)(s + 1);
      for (;;) {
        u32 mn = 0xFFFFFFFFu;
        for (int m = mlo; m <= mhi; ++m) {
          u32 v = (lane < LWGS) ? agent_load(&flags[m * 64 + lane]) : 0xFFFFFFFFu;
          mn = (v < mn) ? v : mn;
        }
        u32 o;
        o = (u32)__shfl_xor((int)mn, 32); mn = (o < mn) ? o : mn;
        o = (u32)__shfl_xor((int)mn, 16); mn = (o < mn) ? o : mn;
        o = (u32)__shfl_xor((int)mn, 8);  mn = (o < mn) ? o : mn;
        o = (u32)__shfl_xor((int)mn, 4);  mn = (o < mn) ? o : mn;
        o = (u32)__shfl_xor((int)mn, 2);  mn = (o < mn) ? o : mn;
        o = (u32)__shfl_xor((int)mn, 1);  mn = (o < mn) ? o : mn;
        if (mn >= need) break;
        __builtin_amdgcn_s_sleep(1);
        if (--budget < 0) break;
      }
    }
    __syncthreads();            // A: flags satisfied for whole block
    __threadfence();            // acquire side for slot reads

    // ---- stage v = [x || h] per owned layer ----
#pragma unroll
    for (int sel = 0; sel < 2; ++sel) {
      int L = l_lo + sel;
      if (L <= l_hi) {
        int t = s - L;
        if (t >= 0 && t < SEQ) {
          const u32* hsrc = slots + (size_t)(L * 2 + ((t + 1) & 1)) * 512;
          const u32* xsrc = (L == 0) ? (X0 + (size_t)t * 512)
                                     : (slots + (size_t)((L - 1) * 2 + (t & 1)) * 512);
#pragma unroll
          for (int rr2 = 0; rr2 < 4; ++rr2) {
            int gidx = tid + rr2 * 256;
            u32 val;
            if (gidx < 512) val = (L == 0) ? xsrc[gidx] : agent_load(&xsrc[gidx]);
            else            val = agent_load(&hsrc[gidx - 512]);
            vlds[sel][(gidx >> 4) * 20 + (gidx & 15)] = val;
          }
        }
      }
    }
    __syncthreads();            // B: vlds ready

    // ---- 20 row dots per wave (12 VGPR rows + 8 LDS rows) ----
    {
      int curl = -1;
      u32 vreg[16];
#pragma unroll
      for (int i = 0; i < RPW; ++i) {
        int rr = wv * RPW + i;
        int p = rr >> 2;
        int g = wg * PAIRS + p;
        int lg = g >> 10;
        int t = s - lg;
        if (t >= 0 && t < SEQ) {
          if (lg != curl) {
            curl = lg;
            const u32* vb = &vlds[lg - l_lo][lane * 20];
#pragma unroll
            for (int d = 0; d < 16; ++d) vreg[d] = vb[d];
          }
          float a0 = 0.f, a1 = 0.f, a2 = 0.f, a3 = 0.f;
          if (i < NVR) {
#pragma unroll
            for (int d = 0; d < 16; d += 4) {
              a0 = fmaf(bflo(W[i][d]),   bflo(vreg[d]),   a0);
              a0 = fmaf(bfhi(W[i][d]),   bfhi(vreg[d]),   a0);
              a1 = fmaf(bflo(W[i][d+1]), bflo(vreg[d+1]), a1);
              a1 = fmaf(bfhi(W[i][d+1]), bfhi(vreg[d+1]), a1);
              a2 = fmaf(bflo(W[i][d+2]), bflo(vreg[d+2]), a2);
              a2 = fmaf(bfhi(W[i][d+2]), bfhi(vreg[d+2]), a2);
              a3 = fmaf(bflo(W[i][d+3]), bflo(vreg[d+3]), a3);
              a3 = fmaf(bfhi(W[i][d+3]), bfhi(vreg[d+3]), a3);
            }
          } else {
            const u32* wl = &wlds[(((wv * NLR) + (i - NVR)) * 16) * 64 + lane];
#pragma unroll
            for (int d = 0; d < 16; d += 4) {
              u32 w0 = wl[d * 64], w1 = wl[(d+1) * 64], w2 = wl[(d+2) * 64], w3 = wl[(d+3) * 64];
              a0 = fmaf(bflo(w0), bflo(vreg[d]),   a0);
              a0 = fmaf(bfhi(w0), bfhi(vreg[d]),   a0);
              a1 = fmaf(bflo(w1), bflo(vreg[d+1]), a1);
              a1 = fmaf(bfhi(w1), bfhi(vreg[d+1]), a1);
              a2 = fmaf(bflo(w2), bflo(vreg[d+2]), a2);
              a2 = fmaf(bfhi(w2), bfhi(vreg[d+2]), a2);
              a3 = fmaf(bflo(w3), bflo(vreg[d+3]), a3);
              a3 = fmaf(bfhi(w3), bfhi(vreg[d+3]), a3);
            }
          }
          float r = (a0 + a1) + (a2 + a3);
          r += __shfl_xor(r, 32);
          r += __shfl_xor(r, 16);
          r += __shfl_xor(r, 8);
          r += __shfl_xor(r, 4);
          r += __shfl_xor(r, 2);
          r += __shfl_xor(r, 1);
          if (lane == 0) zrow[rr] = r;
        }
      }
    }
    __syncthreads();            // C: zrow ready

    // ---- wave0: gates + cell update + publish + flags ----
    if (wv == 0) {
      u16 hb = 0;
      int g = wg * PAIRS + lane;     // valid for lane < PAIRS
      int lg = g >> 10;
      int t = s - lg;
      bool act = (lane < PAIRS) && (t >= 0) && (t < SEQ);
      if (act) {
        float zi = zrow[lane * 4 + 0] + b0;
        float zf = zrow[lane * 4 + 1] + b1g;
        float zg = zrow[lane * 4 + 2] + b2g;
        float zo = zrow[lane * 4 + 3] + b3g;
        float ig = sigm(zi), fg = sigm(zf), gg = tanh_f(zg), og = sigm(zo);
        float c = fg * cst + ig * gg;
        cst = c;
        hb = f2bf(og * tanh_f(c));
      }
      u16 hnb = (u16)__shfl_xor((int)hb, 1);    // partner's h
      if (act && ((lane & 1) == 0)) {
        int j = g & 1023;
        u32 v = (u32)hb | ((u32)hnb << 16);
        agent_store(&slots[(size_t)(lg * 2 + (t & 1)) * 512 + (j >> 1)], v);
        if (lg == NL - 1) H5[(size_t)t * 512 + (j >> 1)] = v;
      }
      __threadfence();                           // wave-level: drain publish stores
      if (lane == 0) {                           // step s complete: flag = s+2
        agent_store(&flags[l_lo * 64 + (wg - f_lo)], (u32)(s + 2));
        if (l_hi != l_lo) agent_store(&flags[l_hi * 64 + (wg - f_hi)], (u32)(s + 2));
      }
    }
  }
}

// ---------------- K3: out = tanh(leaky_relu(h5) @ w2.T + b2) ----------------
__global__ void __launch_bounds__(256) k_out(const u32* __restrict__ H5,
                                             const void* __restrict__ w2,
                                             const void* __restrict__ b2,
                                             void* __restrict__ out,
                                             const u32* __restrict__ flagp) {
  const u32 isf = *flagp;
  int t = blockIdx.x, tid = threadIdx.x;
  __shared__ float hs[1024];
  __shared__ float part[256];
#pragma unroll
  for (int r = 0; r < 2; ++r) {
    int idx = tid + r * 256;
    u32 v = H5[(size_t)t * 512 + idx];
    hs[2 * idx]     = lrelu(bflo(v));
    hs[2 * idx + 1] = lrelu(bfhi(v));
  }
  __syncthreads();
  int n = tid & 63, qq = tid >> 6;
  float a = 0.f;
  if (isf) {
    const float* wr = (const float*)w2 + (size_t)n * 1024 + qq * 256;
    const float* hb = &hs[qq * 256];
#pragma unroll
    for (int d = 0; d < 256; ++d) a = fmaf(wr[d], hb[d], a);
  } else {
    const u32* wr = (const u32*)w2 + (size_t)n * 512 + qq * 128;
    const float* hb = &hs[qq * 256];
#pragma unroll
    for (int d = 0; d < 128; ++d) {
      u32 w = wr[d];
      a = fmaf(bflo(w), hb[2 * d], a);
      a = fmaf(bfhi(w), hb[2 * d + 1], a);
    }
  }
  part[tid] = a;
  __syncthreads();
  if (tid < 64) {
    float bb = isf ? ((const float*)b2)[tid] : bf2f(((const u16*)b2)[tid]);
    float y = part[tid] + part[tid + 64] + part[tid + 128] + part[tid + 192] + bb;
    float r = tanh_f(y);
    if (isf) ((float*)out)[(size_t)t * 64 + tid] = r;
    else     ((u16*)out)[(size_t)t * 64 + tid] = f2bf(r);
  }
}

// ---------------- launcher ----------------
extern "C" void kernel_launch(void* const* d_in, const int* in_sizes, int n_in,
                              void* d_out, int out_size, void* d_ws, size_t ws_size,
                              hipStream_t stream) {
  (void)in_sizes; (void)n_in; (void)out_size;
  if (ws_size < WS_NEED) return;

  const void* din = d_in[0];
  const void* w1  = d_in[1];
  const void* b1  = d_in[2];
  const void* Wih = d_in[3];
  const void* Whh = d_in[4];
  const void* bih = d_in[5];
  const void* bhh = d_in[6];
  const void* w2  = d_in[7];
  const void* b2  = d_in[8];
  const void* h0  = d_in[9];
  const void* c0  = d_in[10];

  char* ws = (char*)d_ws;
  u32* X0    = (u32*)(ws + WS_X0);
  u32* H5    = (u32*)(ws + WS_H5);
  u32* slot  = (u32*)(ws + WS_SLOT);
  u32* flags = (u32*)(ws + WS_SYNC);
  u32* dflag = (u32*)(ws + WS_SYNC + 2048);

  hipMemsetAsync(flags, 0, 4096, stream);      // zero flags + dtype word (ws poisoned 0xAA)
  k_detect<<<1, 64, 0, stream>>>((const u32*)w1, dflag);
  k_in  <<<SEQ, 256, 0, stream>>>(din, w1, b1, X0, dflag);
  k_wave<<<NWG, TPB, 0, stream>>>(Wih, Whh, bih, bhh, h0, c0, X0, H5, slot, flags, dflag);
  k_out <<<SEQ, 256, 0, stream>>>(H5, w2, b2, d_out, dflag);
}

// Round 5
// 145937.988 us; speedup vs baseline: 6.0877x; 1.7247x over previous
//
#include <hip/hip_runtime.h>
#include <stdint.h>

typedef unsigned int  u32;
typedef unsigned short u16;

#define SEQ    8192
#define HID    1024
#define NL     5
#define NWG    256
#define TPB    256
#define PAIRS  20                 // (layer,unit) pairs per WG; NWG*PAIRS = NL*HID
#define RPW    20                 // gate-rows per wave (4 waves * 20 = 80 = PAIRS*4)
#define NVR    12                 // rows kept in VGPRs per wave
#define NLR    8                  // rows kept in LDS per wave (NVR+NLR == RPW)
#define WSTEPS (SEQ + NL - 1)     // 8196 wavefront steps
#define LWGS   52                 // producer WGs per layer
#define RING   8                  // slot ring depth (WAR slack = RING-2 steps)

// ---- workspace layout (bytes) ----
#define WS_X0    ((size_t)0)                        // 8192*512 u32 = 16 MiB (bf16 packed)
#define WS_H5    ((size_t)16*1024*1024)             // 16 MiB
#define WS_SLOT  ((size_t)32*1024*1024)             // 5*8*512 u32 = 80 KiB (pad 128 KiB)
#define WS_SYNC  (WS_SLOT + (size_t)128*1024)       // flags[5][64] u32; dtype flag @+2048
#define WS_NEED  (WS_SYNC + 4096)

// ---------------- helpers ----------------
__device__ __forceinline__ float bf2f(u16 v) { return __uint_as_float(((u32)v) << 16); }
__device__ __forceinline__ float bflo(u32 v) { return __uint_as_float(v << 16); }
__device__ __forceinline__ float bfhi(u32 v) { return __uint_as_float(v & 0xffff0000u); }

__device__ __forceinline__ u16 f2bf(float f) {            // round-to-nearest-even
  u32 u = __float_as_uint(f);
  u32 r = u + 0x7fffu + ((u >> 16) & 1u);
  return (u16)(r >> 16);
}
__device__ __forceinline__ float lrelu(float x) { return (x >= 0.f) ? x : 0.01f * x; }
__device__ __forceinline__ float sigm(float x)  { return 1.f / (1.f + __expf(-x)); }
__device__ __forceinline__ float tanh_f(float x) {
  float e = __expf(-2.f * fabsf(x));
  float t = (1.f - e) / (1.f + e);
  return (x >= 0.f) ? t : -t;
}

// software packed-bf16x2 dot (bit-exact unpack + f32 fma) — proven path
__device__ __forceinline__ float dot2bf(u32 w, u32 v, float acc) {
  return fmaf(bfhi(w), bfhi(v), fmaf(bflo(w), bflo(v), acc));
}

// hardware v_dot2_f32_bf16 — validated at runtime by k_detect before use
#if defined(__has_builtin)
#if __has_builtin(__builtin_amdgcn_fdot2_f32_bf16)
#define HAS_DOT2 1
typedef __bf16 bf16x2 __attribute__((ext_vector_type(2)));
__device__ __forceinline__ float hwdot2(u32 a, u32 b, float c) {
  union U { u32 u; bf16x2 v; };
  U x, y; x.u = a; y.u = b;
  return __builtin_amdgcn_fdot2_f32_bf16(x.v, y.v, c, false);
}
#endif
#endif
#ifndef HAS_DOT2
#define HAS_DOT2 0
__device__ __forceinline__ float hwdot2(u32 a, u32 b, float c) { return dot2bf(a, b, c); }
#endif

__device__ __forceinline__ u32 agent_load(const u32* p) {
  return __hip_atomic_load((u32*)p, __ATOMIC_RELAXED, __HIP_MEMORY_SCOPE_AGENT);
}
__device__ __forceinline__ void agent_store(u32* p, u32 v) {
  __hip_atomic_store(p, v, __ATOMIC_RELAXED, __HIP_MEMORY_SCOPE_AGENT);
}

__device__ __forceinline__ int first_wg(int l) { return (l << 10) / PAIRS; }  // {0,51,102,153,204}

// ---------------- K0: dtype probe + dot2 validation ----------------
__global__ void k_detect(const u32* __restrict__ w1, u32* __restrict__ flag) {
  int lane = threadIdx.x;       // 64 threads
  int cnt = 0;
#pragma unroll
  for (int i = 0; i < 4; ++i) {
    u32 w = w1[lane * 4 + i];
    u32 e = (w >> 23) & 0xffu;
    cnt += (e >= 100u && e <= 140u) ? 1 : 0;
  }
  cnt += __shfl_xor(cnt, 32); cnt += __shfl_xor(cnt, 16); cnt += __shfl_xor(cnt, 8);
  cnt += __shfl_xor(cnt, 4);  cnt += __shfl_xor(cnt, 2);  cnt += __shfl_xor(cnt, 1);
  if (lane == 0) {
    u32 f = (cnt > 128) ? 1u : 0u;
#if HAS_DOT2
    // exact-representable bf16 test vectors
    u32 a1 = (u32)f2bf(1.5f)   | ((u32)f2bf(-2.25f) << 16);
    u32 b1v = (u32)f2bf(0.5f)  | ((u32)f2bf(4.0f)   << 16);
    u32 a2 = (u32)f2bf(0.125f) | ((u32)f2bf(3.0f)   << 16);
    u32 b2v = (u32)f2bf(8.0f)  | ((u32)f2bf(-0.5f)  << 16);
    float t1 = hwdot2(a1, b1v, 1.0f);   // 1 + 0.75 - 9   = -7.25
    float t2 = hwdot2(a2, b2v, 0.5f);   // 0.5 + 1 - 1.5  = 0
    if (fabsf(t1 + 7.25f) < 1e-2f && fabsf(t2) < 1e-2f) f |= 2u;
#endif
    *flag = f;
  }
}

// ---------------- K1: X0 = leaky_relu(data_in @ w1.T + b1), stored packed bf16 ----------------
__global__ void __launch_bounds__(256) k_in(const void* __restrict__ din,
                                            const void* __restrict__ w1,
                                            const void* __restrict__ b1,
                                            u32* __restrict__ X0,
                                            const u32* __restrict__ flagp) {
  const u32 isf = *flagp & 1u;
  int t = blockIdx.x, tid = threadIdx.x;
  __shared__ float xs[64];
  if (isf) {
    if (tid < 64) xs[tid] = ((const float*)din)[(size_t)t * 64 + tid];
  } else {
    if (tid < 32) {
      u32 v = ((const u32*)din)[(size_t)t * 32 + tid];
      xs[2 * tid] = bflo(v); xs[2 * tid + 1] = bfhi(v);
    }
  }
  __syncthreads();
  float o[4];
#pragma unroll
  for (int r = 0; r < 4; ++r) {
    int i = tid * 4 + r;
    float a = 0.f;
    if (isf) {
      const float* wr = (const float*)w1 + (size_t)i * 64;
#pragma unroll
      for (int d = 0; d < 64; ++d) a = fmaf(wr[d], xs[d], a);
      a += ((const float*)b1)[i];
    } else {
      const u32* wr = (const u32*)w1 + (size_t)i * 32;
#pragma unroll
      for (int d = 0; d < 32; ++d) {
        u32 w = wr[d];
        a = fmaf(bflo(w), xs[2 * d], a);
        a = fmaf(bfhi(w), xs[2 * d + 1], a);
      }
      a += bf2f(((const u16*)b1)[i]);
    }
    o[r] = lrelu(a);
  }
  X0[(size_t)t * 512 + tid * 2]     = (u32)f2bf(o[0]) | ((u32)f2bf(o[1]) << 16);
  X0[(size_t)t * 512 + tid * 2 + 1] = (u32)f2bf(o[2]) | ((u32)f2bf(o[3]) << 16);
}

// ---------------- K2: persistent wavefront LSTM ----------------
// Slot ring: slots[L][t mod 8][512]. h0 lives in ring index 7 (t = -1).
// Flags: after completing step s, WG stores s+2 into its word of each owned layer.
// Wait before step s: min( flags[l_lo-1..l_hi], flags[l_hi+1] + (RING-2) ) >= s+1.
//   fwd/same-layer edges are true deps (1-step); WAR has RING-2 = 6 steps of slack.
__global__ void __launch_bounds__(TPB, 1) k_wave(const void* __restrict__ WihP,
                                                 const void* __restrict__ WhhP,
                                                 const void* __restrict__ bihP,
                                                 const void* __restrict__ bhhP,
                                                 const void* __restrict__ h0P,
                                                 const void* __restrict__ c0P,
                                                 const u32* __restrict__ X0,
                                                 u32* __restrict__ H5,
                                                 u32* slots, u32* flags,
                                                 const u32* __restrict__ flagp) {
  const u32 dfl = *flagp;
  const u32 isf = dfl & 1u;
  const bool ud2 = (dfl & 2u) != 0u;
  const int tid  = threadIdx.x;
  const int lane = tid & 63;
  const int wv   = tid >> 6;
  const int wg   = blockIdx.x;

  __shared__ u32   vlds[2][64 * 17];            // [layer-sel][lane*17 + d] (17: odd stride, conflict-free)
  __shared__ u32   wlds[4 * NLR * 1024];        // [wave][row][d4][lane][4] 128 KiB, b128-friendly
  __shared__ float zrow[80];

  // ---- load weights: rows 0..NVR-1 -> VGPRs, rows NVR..19 -> LDS ----
  u32 W[NVR][16];
#pragma unroll
  for (int i = 0; i < RPW; ++i) {
    int rr = wv * RPW + i;
    int p = rr >> 2, q = rr & 3;
    int g = wg * PAIRS + p;
    int lg = g >> 10, j = g & 1023;
    u32 tmp[16];
    if (isf) {
      const float* matf = (lane < 32) ? (const float*)WihP : (const float*)WhhP;
      const float4* s4 = (const float4*)(matf + ((size_t)(lg * 4096 + q * 1024 + j)) * 1024 + (lane & 31) * 32);
#pragma unroll
      for (int q4 = 0; q4 < 8; ++q4) {
        float4 f = s4[q4];
        tmp[q4 * 2]     = (u32)f2bf(f.x) | ((u32)f2bf(f.y) << 16);
        tmp[q4 * 2 + 1] = (u32)f2bf(f.z) | ((u32)f2bf(f.w) << 16);
      }
    } else {
      const u32* mat = (lane < 32) ? (const u32*)WihP : (const u32*)WhhP;
      const uint4* s4 = (const uint4*)(mat + ((size_t)(lg * 4096 + q * 1024 + j)) * 512 + (lane & 31) * 16);
      uint4 a0 = s4[0], a1 = s4[1], a2 = s4[2], a3 = s4[3];
      tmp[0]=a0.x; tmp[1]=a0.y; tmp[2]=a0.z;  tmp[3]=a0.w;
      tmp[4]=a1.x; tmp[5]=a1.y; tmp[6]=a1.z;  tmp[7]=a1.w;
      tmp[8]=a2.x; tmp[9]=a2.y; tmp[10]=a2.z; tmp[11]=a2.w;
      tmp[12]=a3.x;tmp[13]=a3.y;tmp[14]=a3.z; tmp[15]=a3.w;
    }
    if (i < NVR) {
#pragma unroll
      for (int d = 0; d < 16; ++d) W[i][d] = tmp[d];
    } else {
      u32* base = &wlds[(wv * NLR + (i - NVR)) * 1024];
#pragma unroll
      for (int d4 = 0; d4 < 4; ++d4) {
        uint4 v4 = make_uint4(tmp[d4*4], tmp[d4*4+1], tmp[d4*4+2], tmp[d4*4+3]);
        *(uint4*)&base[d4 * 256 + lane * 4] = v4;
      }
    }
  }

  // ---- per-unit state in wave0 registers (lane < PAIRS owns one unit) ----
  float cst = 0.f;
  float b0 = 0.f, b1g = 0.f, b2g = 0.f, b3g = 0.f;
  if (wv == 0 && lane < PAIRS) {
    int g = wg * PAIRS + lane, lg = g >> 10, j = g & 1023;
    cst = isf ? ((const float*)c0P)[lg * 1024 + j] : bf2f(((const u16*)c0P)[lg * 1024 + j]);
#pragma unroll
    for (int q = 0; q < 4; ++q) {
      int r = lg * 4096 + q * 1024 + j;
      float bb = isf ? (((const float*)bihP)[r] + ((const float*)bhhP)[r])
                     : (bf2f(((const u16*)bihP)[r]) + bf2f(((const u16*)bhhP)[r]));
      if (q == 0) b0 = bb; else if (q == 1) b1g = bb; else if (q == 2) b2g = bb; else b3g = bb;
    }
  }
  if (tid < PAIRS / 2) {          // h0 -> ring slot 7 (t = -1)
    int g = wg * PAIRS + 2 * tid, lg = g >> 10, j = g & 1023;
    u32 v;
    if (isf) {
      const float* h0f = (const float*)h0P;
      v = (u32)f2bf(h0f[lg * 1024 + j]) | ((u32)f2bf(h0f[lg * 1024 + j + 1]) << 16);
    } else {
      const u16* h0b = (const u16*)h0P;
      v = (u32)h0b[lg * 1024 + j] | ((u32)h0b[lg * 1024 + j + 1] << 16);
    }
    agent_store(&slots[(size_t)(lg * RING + 7) * 512 + (j >> 1)], v);
  }

  const int l_lo = (wg * PAIRS) >> 10;
  const int l_hi = (wg * PAIRS + PAIRS - 1) >> 10;
  const int mlo = (l_lo > 0) ? l_lo - 1 : 0;
  const bool haswar = (l_hi + 1) < NL;
  const int f_lo = first_wg(l_lo), f_hi = first_wg(l_hi);

  __threadfence();
  __syncthreads();
  if (tid == 0) {                               // init done: flag = 1
    agent_store(&flags[l_lo * 64 + (wg - f_lo)], 1u);
    if (l_hi != l_lo) agent_store(&flags[l_hi * 64 + (wg - f_hi)], 1u);
  }

  int budget = 8000000;                         // bounded polling: never hard-hang

  for (int s = 0; s < WSTEPS; ++s) {
    // ---- wait: min(fwd flags, war flags + RING-2) >= s+1 ----
    if (wv == 0) {
      u32 need = (u32)(s + 1);
      for (;;) {
        u32 mn = 0xFFFFFFFFu;
        if (lane < LWGS) {
          for (int m = mlo; m <= l_hi; ++m) {
            u32 v = agent_load(&flags[m * 64 + lane]);
            mn = (v < mn) ? v : mn;
          }
          if (haswar) {
            u32 v = agent_load(&flags[(l_hi + 1) * 64 + lane]) + (u32)(RING - 2);
            mn = (v < mn) ? v : mn;
          }
        }
        u32 o;
        o = (u32)__shfl_xor((int)mn, 32); mn = (o < mn) ? o : mn;
        o = (u32)__shfl_xor((int)mn, 16); mn = (o < mn) ? o : mn;
        o = (u32)__shfl_xor((int)mn, 8);  mn = (o < mn) ? o : mn;
        o = (u32)__shfl_xor((int)mn, 4);  mn = (o < mn) ? o : mn;
        o = (u32)__shfl_xor((int)mn, 2);  mn = (o < mn) ? o : mn;
        o = (u32)__shfl_xor((int)mn, 1);  mn = (o < mn) ? o : mn;
        if (mn >= need) break;
        __builtin_amdgcn_s_sleep(1);
        if (--budget < 0) break;
      }
    }
    __syncthreads();            // A: deps satisfied for whole block

    // ---- stage v = [x || h] per owned layer (coalesced LLC loads -> LDS) ----
#pragma unroll
    for (int sel = 0; sel < 2; ++sel) {
      int L = l_lo + sel;
      if (L <= l_hi) {
        int t = s - L;
        if (t >= 0 && t < SEQ) {
          const u32* hsrc = slots + (size_t)(L * RING + ((t - 1) & 7)) * 512;
          const u32* xsrc = (L == 0) ? (X0 + (size_t)t * 512)
                                     : (slots + (size_t)((L - 1) * RING + (t & 7)) * 512);
#pragma unroll
          for (int rr2 = 0; rr2 < 4; ++rr2) {
            int gidx = tid + rr2 * 256;
            u32 val;
            if (gidx < 512) val = (L == 0) ? xsrc[gidx] : agent_load(&xsrc[gidx]);
            else            val = agent_load(&hsrc[gidx - 512]);
            vlds[sel][(gidx >> 4) * 17 + (gidx & 15)] = val;
          }
        }
      }
    }
    __syncthreads();            // B: vlds ready

    // ---- 20 row dots per wave (12 VGPR rows + 8 LDS rows) ----
    {
      int curl = -1;
      u32 vreg[16];
#pragma unroll
      for (int i = 0; i < RPW; ++i) {
        int rr = wv * RPW + i;
        int p = rr >> 2;
        int g = wg * PAIRS + p;
        int lg = g >> 10;
        int t = s - lg;
        if (t >= 0 && t < SEQ) {
          if (lg != curl) {
            curl = lg;
            const u32* vb = &vlds[lg - l_lo][lane * 17];
#pragma unroll
            for (int d = 0; d < 16; ++d) vreg[d] = vb[d];
          }
          float a0 = 0.f, a1 = 0.f, a2 = 0.f, a3 = 0.f;
          if (i < NVR) {
            if (ud2) {
#pragma unroll
              for (int d = 0; d < 16; d += 4) {
                a0 = hwdot2(W[i][d],   vreg[d],   a0);
                a1 = hwdot2(W[i][d+1], vreg[d+1], a1);
                a2 = hwdot2(W[i][d+2], vreg[d+2], a2);
                a3 = hwdot2(W[i][d+3], vreg[d+3], a3);
              }
            } else {
#pragma unroll
              for (int d = 0; d < 16; d += 4) {
                a0 = fmaf(bflo(W[i][d]),   bflo(vreg[d]),   a0);
                a0 = fmaf(bfhi(W[i][d]),   bfhi(vreg[d]),   a0);
                a1 = fmaf(bflo(W[i][d+1]), bflo(vreg[d+1]), a1);
                a1 = fmaf(bfhi(W[i][d+1]), bfhi(vreg[d+1]), a1);
                a2 = fmaf(bflo(W[i][d+2]), bflo(vreg[d+2]), a2);
                a2 = fmaf(bfhi(W[i][d+2]), bfhi(vreg[d+2]), a2);
                a3 = fmaf(bflo(W[i][d+3]), bflo(vreg[d+3]), a3);
                a3 = fmaf(bfhi(W[i][d+3]), bfhi(vreg[d+3]), a3);
              }
            }
          } else {
            const uint4* wl = (const uint4*)&wlds[(wv * NLR + (i - NVR)) * 1024 + lane * 4];
#pragma unroll
            for (int d4 = 0; d4 < 4; ++d4) {
              uint4 w4 = wl[d4 * 64];
              if (ud2) {
                a0 = hwdot2(w4.x, vreg[d4*4+0], a0);
                a1 = hwdot2(w4.y, vreg[d4*4+1], a1);
                a2 = hwdot2(w4.z, vreg[d4*4+2], a2);
                a3 = hwdot2(w4.w, vreg[d4*4+3], a3);
              } else {
                a0 = fmaf(bflo(w4.x), bflo(vreg[d4*4+0]), a0);
                a0 = fmaf(bfhi(w4.x), bfhi(vreg[d4*4+0]), a0);
                a1 = fmaf(bflo(w4.y), bflo(vreg[d4*4+1]), a1);
                a1 = fmaf(bfhi(w4.y), bfhi(vreg[d4*4+1]), a1);
                a2 = fmaf(bflo(w4.z), bflo(vreg[d4*4+2]), a2);
                a2 = fmaf(bfhi(w4.z), bfhi(vreg[d4*4+2]), a2);
                a3 = fmaf(bflo(w4.w), bflo(vreg[d4*4+3]), a3);
                a3 = fmaf(bfhi(w4.w), bfhi(vreg[d4*4+3]), a3);
              }
            }
          }
          float r = (a0 + a1) + (a2 + a3);
          r += __shfl_xor(r, 32);
          r += __shfl_xor(r, 16);
          r += __shfl_xor(r, 8);
          r += __shfl_xor(r, 4);
          r += __shfl_xor(r, 2);
          r += __shfl_xor(r, 1);
          if (lane == 0) zrow[rr] = r;
        }
      }
    }
    __syncthreads();            // C: zrow ready

    // ---- wave0: gates + cell update + publish + flags ----
    if (wv == 0) {
      u16 hb = 0;
      int g = wg * PAIRS + lane;     // valid for lane < PAIRS
      int lg = g >> 10;
      int t = s - lg;
      bool act = (lane < PAIRS) && (t >= 0) && (t < SEQ);
      if (act) {
        float zi = zrow[lane * 4 + 0] + b0;
        float zf = zrow[lane * 4 + 1] + b1g;
        float zg = zrow[lane * 4 + 2] + b2g;
        float zo = zrow[lane * 4 + 3] + b3g;
        float ig = sigm(zi), fg = sigm(zf), gg = tanh_f(zg), og = sigm(zo);
        float c = fg * cst + ig * gg;
        cst = c;
        hb = f2bf(og * tanh_f(c));
      }
      u16 hnb = (u16)__shfl_xor((int)hb, 1);
      if (act && ((lane & 1) == 0)) {
        int j = g & 1023;
        u32 v = (u32)hb | ((u32)hnb << 16);
        agent_store(&slots[(size_t)(lg * RING + (t & 7)) * 512 + (j >> 1)], v);
        if (lg == NL - 1) H5[(size_t)t * 512 + (j >> 1)] = v;
      }
      __threadfence();                           // release: drain publish stores
      if (lane == 0) {                           // step s complete: flag = s+2
        agent_store(&flags[l_lo * 64 + (wg - f_lo)], (u32)(s + 2));
        if (l_hi != l_lo) agent_store(&flags[l_hi * 64 + (wg - f_hi)], (u32)(s + 2));
      }
    }
  }
}

// ---------------- K3: out = tanh(leaky_relu(h5) @ w2.T + b2) ----------------
__global__ void __launch_bounds__(256) k_out(const u32* __restrict__ H5,
                                             const void* __restrict__ w2,
                                             const void* __restrict__ b2,
                                             void* __restrict__ out,
                                             const u32* __restrict__ flagp) {
  const u32 isf = *flagp & 1u;
  int t = blockIdx.x, tid = threadIdx.x;
  __shared__ float hs[1024];
  __shared__ float part[256];
#pragma unroll
  for (int r = 0; r < 2; ++r) {
    int idx = tid + r * 256;
    u32 v = H5[(size_t)t * 512 + idx];
    hs[2 * idx]     = lrelu(bflo(v));
    hs[2 * idx + 1] = lrelu(bfhi(v));
  }
  __syncthreads();
  int n = tid & 63, qq = tid >> 6;
  float a = 0.f;
  if (isf) {
    const float* wr = (const float*)w2 + (size_t)n * 1024 + qq * 256;
    const float* hb = &hs[qq * 256];
#pragma unroll
    for (int d = 0; d < 256; ++d) a = fmaf(wr[d], hb[d], a);
  } else {
    const u32* wr = (const u32*)w2 + (size_t)n * 512 + qq * 128;
    const float* hb = &hs[qq * 256];
#pragma unroll
    for (int d = 0; d < 128; ++d) {
      u32 w = wr[d];
      a = fmaf(bflo(w), hb[2 * d], a);
      a = fmaf(bfhi(w), hb[2 * d + 1], a);
    }
  }
  part[tid] = a;
  __syncthreads();
  if (tid < 64) {
    float bb = isf ? ((const float*)b2)[tid] : bf2f(((const u16*)b2)[tid]);
    float y = part[tid] + part[tid + 64] + part[tid + 128] + part[tid + 192] + bb;
    float r = tanh_f(y);
    if (isf) ((float*)out)[(size_t)t * 64 + tid] = r;
    else     ((u16*)out)[(size_t)t * 64 + tid] = f2bf(r);
  }
}

// ---------------- launcher ----------------
extern "C" void kernel_launch(void* const* d_in, const int* in_sizes, int n_in,
                              void* d_out, int out_size, void* d_ws, size_t ws_size,
                              hipStream_t stream) {
  (void)in_sizes; (void)n_in; (void)out_size;
  if (ws_size < WS_NEED) return;

  const void* din = d_in[0];
  const void* w1  = d_in[1];
  const void* b1  = d_in[2];
  const void* Wih = d_in[3];
  const void* Whh = d_in[4];
  const void* bih = d_in[5];
  const void* bhh = d_in[6];
  const void* w2  = d_in[7];
  const void* b2  = d_in[8];
  const void* h0  = d_in[9];
  const void* c0  = d_in[10];

  char* ws = (char*)d_ws;
  u32* X0    = (u32*)(ws + WS_X0);
  u32* H5    = (u32*)(ws + WS_H5);
  u32* slot  = (u32*)(ws + WS_SLOT);
  u32* flags = (u32*)(ws + WS_SYNC);
  u32* dflag = (u32*)(ws + WS_SYNC + 2048);

  hipMemsetAsync(flags, 0, 4096, stream);      // zero flags + dtype word (ws poisoned 0xAA)
  k_detect<<<1, 64, 0, stream>>>((const u32*)w1, dflag);
  k_in  <<<SEQ, 256, 0, stream>>>(din, w1, b1, X0, dflag);
  k_wave<<<NWG, TPB, 0, stream>>>(Wih, Whh, bih, bhh, h0, c0, X0, H5, slot, flags, dflag);
  k_out <<<SEQ, 256, 0, stream>>>(H5, w2, b2, d_out, dflag);
}

// Round 6
// 116669.080 us; speedup vs baseline: 7.6149x; 1.2509x over previous
//
#include <hip/hip_runtime.h>
#include <stdint.h>

typedef unsigned int  u32;
typedef unsigned short u16;

#define SEQ    8192
#define HID    1024
#define NL     5
#define NWG    256
#define TPB    256
#define PAIRS  20                 // (layer,unit) pairs per WG; NWG*PAIRS = NL*HID
#define RPW    20                 // gate-rows per wave (4 waves * 20 = 80 = PAIRS*4)
#define NVR    12                 // rows kept in VGPRs per wave
#define NLR    8                  // rows kept in LDS per wave (NVR+NLR == RPW)
#define WSTEPS (SEQ + NL - 1)     // 8196 wavefront steps
#define LWGS   52                 // producer WGs per layer
#define RING   8                  // slot ring depth (WAR slack = RING-2 steps)

// ---- workspace layout (bytes) ----
#define WS_X0    ((size_t)0)                        // 8192*512 u32 = 16 MiB (bf16 packed)
#define WS_H5    ((size_t)16*1024*1024)             // 16 MiB
#define WS_SLOT  ((size_t)32*1024*1024)             // 5*8*512 u32 = 80 KiB (pad 128 KiB)
#define WS_SYNC  (WS_SLOT + (size_t)128*1024)       // flags[5][64] u32; dtype flag @+2048
#define WS_NEED  (WS_SYNC + 4096)

// ---------------- helpers ----------------
__device__ __forceinline__ float bf2f(u16 v) { return __uint_as_float(((u32)v) << 16); }
__device__ __forceinline__ float bflo(u32 v) { return __uint_as_float(v << 16); }
__device__ __forceinline__ float bfhi(u32 v) { return __uint_as_float(v & 0xffff0000u); }

__device__ __forceinline__ u16 f2bf(float f) {            // round-to-nearest-even
  u32 u = __float_as_uint(f);
  u32 r = u + 0x7fffu + ((u >> 16) & 1u);
  return (u16)(r >> 16);
}
__device__ __forceinline__ float lrelu(float x) { return (x >= 0.f) ? x : 0.01f * x; }
__device__ __forceinline__ float sigm(float x)  { return 1.f / (1.f + __expf(-x)); }
__device__ __forceinline__ float tanh_f(float x) {
  float e = __expf(-2.f * fabsf(x));
  float t = (1.f - e) / (1.f + e);
  return (x >= 0.f) ? t : -t;
}

// software packed-bf16x2 dot (bit-exact unpack + f32 fma) — proven fallback
__device__ __forceinline__ float dot2bf(u32 w, u32 v, float acc) {
  return fmaf(bfhi(w), bfhi(v), fmaf(bflo(w), bflo(v), acc));
}

// hardware v_dot2_f32_bf16 — validated at runtime by k_detect before use
#if defined(__has_builtin)
#if __has_builtin(__builtin_amdgcn_fdot2_f32_bf16)
#define HAS_DOT2 1
typedef __bf16 bf16x2 __attribute__((ext_vector_type(2)));
__device__ __forceinline__ float hwdot2(u32 a, u32 b, float c) {
  union U { u32 u; bf16x2 v; };
  U x, y; x.u = a; y.u = b;
  return __builtin_amdgcn_fdot2_f32_bf16(x.v, y.v, c, false);
}
#endif
#endif
#ifndef HAS_DOT2
#define HAS_DOT2 0
__device__ __forceinline__ float hwdot2(u32 a, u32 b, float c) { return dot2bf(a, b, c); }
#endif

__device__ __forceinline__ u32 agent_load(const u32* p) {
  return __hip_atomic_load((u32*)p, __ATOMIC_RELAXED, __HIP_MEMORY_SCOPE_AGENT);
}
__device__ __forceinline__ void agent_store(u32* p, u32 v) {
  __hip_atomic_store(p, v, __ATOMIC_RELAXED, __HIP_MEMORY_SCOPE_AGENT);
}

// Release ordering for LLC-routed (sc1 atomic) stores WITHOUT the agent-fence
// L2 writeback/invalidate: vmcnt(0) means all prior sc1 stores have reached the
// LLC coherence point; a subsequent flag store is then globally ordered after
// them. "memory" clobber pins compiler ordering.
__device__ __forceinline__ void rel_drain() {
  asm volatile("s_waitcnt vmcnt(0)" ::: "memory");
}

__device__ __forceinline__ int first_wg(int l) { return (l << 10) / PAIRS; }  // {0,51,102,153,204}

// ---------------- K0: dtype probe + dot2 validation ----------------
__global__ void k_detect(const u32* __restrict__ w1, u32* __restrict__ flag) {
  int lane = threadIdx.x;       // 64 threads
  int cnt = 0;
#pragma unroll
  for (int i = 0; i < 4; ++i) {
    u32 w = w1[lane * 4 + i];
    u32 e = (w >> 23) & 0xffu;
    cnt += (e >= 100u && e <= 140u) ? 1 : 0;
  }
  cnt += __shfl_xor(cnt, 32); cnt += __shfl_xor(cnt, 16); cnt += __shfl_xor(cnt, 8);
  cnt += __shfl_xor(cnt, 4);  cnt += __shfl_xor(cnt, 2);  cnt += __shfl_xor(cnt, 1);
  if (lane == 0) {
    u32 f = (cnt > 128) ? 1u : 0u;
#if HAS_DOT2
    u32 a1 = (u32)f2bf(1.5f)   | ((u32)f2bf(-2.25f) << 16);
    u32 b1v = (u32)f2bf(0.5f)  | ((u32)f2bf(4.0f)   << 16);
    u32 a2 = (u32)f2bf(0.125f) | ((u32)f2bf(3.0f)   << 16);
    u32 b2v = (u32)f2bf(8.0f)  | ((u32)f2bf(-0.5f)  << 16);
    float t1 = hwdot2(a1, b1v, 1.0f);   // 1 + 0.75 - 9   = -7.25
    float t2 = hwdot2(a2, b2v, 0.5f);   // 0.5 + 1 - 1.5  = 0
    if (fabsf(t1 + 7.25f) < 1e-2f && fabsf(t2) < 1e-2f) f |= 2u;
#endif
    *flag = f;
  }
}

// ---------------- K1: X0 = leaky_relu(data_in @ w1.T + b1), stored packed bf16 ----------------
__global__ void __launch_bounds__(256) k_in(const void* __restrict__ din,
                                            const void* __restrict__ w1,
                                            const void* __restrict__ b1,
                                            u32* __restrict__ X0,
                                            const u32* __restrict__ flagp) {
  const u32 isf = *flagp & 1u;
  int t = blockIdx.x, tid = threadIdx.x;
  __shared__ float xs[64];
  if (isf) {
    if (tid < 64) xs[tid] = ((const float*)din)[(size_t)t * 64 + tid];
  } else {
    if (tid < 32) {
      u32 v = ((const u32*)din)[(size_t)t * 32 + tid];
      xs[2 * tid] = bflo(v); xs[2 * tid + 1] = bfhi(v);
    }
  }
  __syncthreads();
  float o[4];
#pragma unroll
  for (int r = 0; r < 4; ++r) {
    int i = tid * 4 + r;
    float a = 0.f;
    if (isf) {
      const float* wr = (const float*)w1 + (size_t)i * 64;
#pragma unroll
      for (int d = 0; d < 64; ++d) a = fmaf(wr[d], xs[d], a);
      a += ((const float*)b1)[i];
    } else {
      const u32* wr = (const u32*)w1 + (size_t)i * 32;
#pragma unroll
      for (int d = 0; d < 32; ++d) {
        u32 w = wr[d];
        a = fmaf(bflo(w), xs[2 * d], a);
        a = fmaf(bfhi(w), xs[2 * d + 1], a);
      }
      a += bf2f(((const u16*)b1)[i]);
    }
    o[r] = lrelu(a);
  }
  X0[(size_t)t * 512 + tid * 2]     = (u32)f2bf(o[0]) | ((u32)f2bf(o[1]) << 16);
  X0[(size_t)t * 512 + tid * 2 + 1] = (u32)f2bf(o[2]) | ((u32)f2bf(o[3]) << 16);
}

// ---------------- K2: persistent wavefront LSTM ----------------
// Slot ring: slots[L][t mod 8][512]. h0 lives in ring index 7 (t = -1).
// Flags: after completing step s, WG stores s+2 into its word of each owned layer.
// Wait before step s: min( flags[l_lo-1..l_hi], flags[l_hi+1] + (RING-2) ) >= s+1.
// All cross-WG traffic is sc1 LLC-routed atomics; release ordering = vmcnt drain
// (rel_drain), NOT __threadfence (which costs an L2 writeback/inv per call on
// multi-XCD gfx95x and sat on the inter-step critical path in R5).
__global__ void __launch_bounds__(TPB, 1) k_wave(const void* __restrict__ WihP,
                                                 const void* __restrict__ WhhP,
                                                 const void* __restrict__ bihP,
                                                 const void* __restrict__ bhhP,
                                                 const void* __restrict__ h0P,
                                                 const void* __restrict__ c0P,
                                                 const u32* __restrict__ X0,
                                                 u32* __restrict__ H5,
                                                 u32* slots, u32* flags,
                                                 const u32* __restrict__ flagp) {
  const u32 dfl = *flagp;
  const u32 isf = dfl & 1u;
  const bool ud2 = (dfl & 2u) != 0u;
  const int tid  = threadIdx.x;
  const int lane = tid & 63;
  const int wv   = tid >> 6;
  const int wg   = blockIdx.x;

  __shared__ u32   vlds[2][64 * 17];            // [layer-sel][lane*17 + d] (odd stride: conflict-free)
  __shared__ u32   wlds[4 * NLR * 1024];        // [wave][row][d4][lane][4] 128 KiB, b128-friendly
  __shared__ float zrow[80];

  // ---- load weights: rows 0..NVR-1 -> VGPRs, rows NVR..19 -> LDS ----
  u32 W[NVR][16];
#pragma unroll
  for (int i = 0; i < RPW; ++i) {
    int rr = wv * RPW + i;
    int p = rr >> 2, q = rr & 3;
    int g = wg * PAIRS + p;
    int lg = g >> 10, j = g & 1023;
    u32 tmp[16];
    if (isf) {
      const float* matf = (lane < 32) ? (const float*)WihP : (const float*)WhhP;
      const float4* s4 = (const float4*)(matf + ((size_t)(lg * 4096 + q * 1024 + j)) * 1024 + (lane & 31) * 32);
#pragma unroll
      for (int q4 = 0; q4 < 8; ++q4) {
        float4 f = s4[q4];
        tmp[q4 * 2]     = (u32)f2bf(f.x) | ((u32)f2bf(f.y) << 16);
        tmp[q4 * 2 + 1] = (u32)f2bf(f.z) | ((u32)f2bf(f.w) << 16);
      }
    } else {
      const u32* mat = (lane < 32) ? (const u32*)WihP : (const u32*)WhhP;
      const uint4* s4 = (const uint4*)(mat + ((size_t)(lg * 4096 + q * 1024 + j)) * 512 + (lane & 31) * 16);
      uint4 a0 = s4[0], a1 = s4[1], a2 = s4[2], a3 = s4[3];
      tmp[0]=a0.x; tmp[1]=a0.y; tmp[2]=a0.z;  tmp[3]=a0.w;
      tmp[4]=a1.x; tmp[5]=a1.y; tmp[6]=a1.z;  tmp[7]=a1.w;
      tmp[8]=a2.x; tmp[9]=a2.y; tmp[10]=a2.z; tmp[11]=a2.w;
      tmp[12]=a3.x;tmp[13]=a3.y;tmp[14]=a3.z; tmp[15]=a3.w;
    }
    if (i < NVR) {
#pragma unroll
      for (int d = 0; d < 16; ++d) W[i][d] = tmp[d];
    } else {
      u32* base = &wlds[(wv * NLR + (i - NVR)) * 1024];
#pragma unroll
      for (int d4 = 0; d4 < 4; ++d4) {
        uint4 v4 = make_uint4(tmp[d4*4], tmp[d4*4+1], tmp[d4*4+2], tmp[d4*4+3]);
        *(uint4*)&base[d4 * 256 + lane * 4] = v4;
      }
    }
  }

  // ---- per-unit state in wave0 registers (lane < PAIRS owns one unit) ----
  float cst = 0.f;
  float b0 = 0.f, b1g = 0.f, b2g = 0.f, b3g = 0.f;
  if (wv == 0 && lane < PAIRS) {
    int g = wg * PAIRS + lane, lg = g >> 10, j = g & 1023;
    cst = isf ? ((const float*)c0P)[lg * 1024 + j] : bf2f(((const u16*)c0P)[lg * 1024 + j]);
#pragma unroll
    for (int q = 0; q < 4; ++q) {
      int r = lg * 4096 + q * 1024 + j;
      float bb = isf ? (((const float*)bihP)[r] + ((const float*)bhhP)[r])
                     : (bf2f(((const u16*)bihP)[r]) + bf2f(((const u16*)bhhP)[r]));
      if (q == 0) b0 = bb; else if (q == 1) b1g = bb; else if (q == 2) b2g = bb; else b3g = bb;
    }
  }
  if (tid < PAIRS / 2) {          // h0 -> ring slot 7 (t = -1)
    int g = wg * PAIRS + 2 * tid, lg = g >> 10, j = g & 1023;
    u32 v;
    if (isf) {
      const float* h0f = (const float*)h0P;
      v = (u32)f2bf(h0f[lg * 1024 + j]) | ((u32)f2bf(h0f[lg * 1024 + j + 1]) << 16);
    } else {
      const u16* h0b = (const u16*)h0P;
      v = (u32)h0b[lg * 1024 + j] | ((u32)h0b[lg * 1024 + j + 1] << 16);
    }
    agent_store(&slots[(size_t)(lg * RING + 7) * 512 + (j >> 1)], v);
  }

  const int l_lo = (wg * PAIRS) >> 10;
  const int l_hi = (wg * PAIRS + PAIRS - 1) >> 10;
  const int mlo = (l_lo > 0) ? l_lo - 1 : 0;
  const bool haswar = (l_hi + 1) < NL;
  const int f_lo = first_wg(l_lo), f_hi = first_wg(l_hi);

  __threadfence();                              // once: full fence before first flag
  __syncthreads();
  if (tid == 0) {                               // init done: flag = 1
    agent_store(&flags[l_lo * 64 + (wg - f_lo)], 1u);
    if (l_hi != l_lo) agent_store(&flags[l_hi * 64 + (wg - f_hi)], 1u);
  }

  int budget = 20000000;                        // bounded polling: never hard-hang

  for (int s = 0; s < WSTEPS; ++s) {
    // ---- wait: min(fwd flags, war flags + RING-2) >= s+1 ----
    if (wv == 0) {
      u32 need = (u32)(s + 1);
      for (;;) {
        u32 mn = 0xFFFFFFFFu;
        if (lane < LWGS) {
          for (int m = mlo; m <= l_hi; ++m) {
            u32 v = agent_load(&flags[m * 64 + lane]);
            mn = (v < mn) ? v : mn;
          }
          if (haswar) {
            u32 v = agent_load(&flags[(l_hi + 1) * 64 + lane]) + (u32)(RING - 2);
            mn = (v < mn) ? v : mn;
          }
        }
        u32 o;
        o = (u32)__shfl_xor((int)mn, 32); mn = (o < mn) ? o : mn;
        o = (u32)__shfl_xor((int)mn, 16); mn = (o < mn) ? o : mn;
        o = (u32)__shfl_xor((int)mn, 8);  mn = (o < mn) ? o : mn;
        o = (u32)__shfl_xor((int)mn, 4);  mn = (o < mn) ? o : mn;
        o = (u32)__shfl_xor((int)mn, 2);  mn = (o < mn) ? o : mn;
        o = (u32)__shfl_xor((int)mn, 1);  mn = (o < mn) ? o : mn;
        if (mn >= need) break;
        if (--budget < 0) break;
      }
    }
    __syncthreads();            // A: deps satisfied for whole block

    // ---- stage v = [x || h] per owned layer (coalesced LLC loads -> LDS) ----
#pragma unroll
    for (int sel = 0; sel < 2; ++sel) {
      int L = l_lo + sel;
      if (L <= l_hi) {
        int t = s - L;
        if (t >= 0 && t < SEQ) {
          const u32* hsrc = slots + (size_t)(L * RING + ((t - 1) & 7)) * 512;
          const u32* xsrc = (L == 0) ? (X0 + (size_t)t * 512)
                                     : (slots + (size_t)((L - 1) * RING + (t & 7)) * 512);
#pragma unroll
          for (int rr2 = 0; rr2 < 4; ++rr2) {
            int gidx = tid + rr2 * 256;
            u32 val;
            if (gidx < 512) val = (L == 0) ? xsrc[gidx] : agent_load(&xsrc[gidx]);
            else            val = agent_load(&hsrc[gidx - 512]);
            vlds[sel][(gidx >> 4) * 17 + (gidx & 15)] = val;
          }
        }
      }
    }
    __syncthreads();            // B: vlds ready

    // ---- 20 row dots per wave (12 VGPR rows + 8 LDS rows) ----
    {
      int curl = -1;
      u32 vreg[16];
#pragma unroll
      for (int i = 0; i < RPW; ++i) {
        int rr = wv * RPW + i;
        int p = rr >> 2;
        int g = wg * PAIRS + p;
        int lg = g >> 10;
        int t = s - lg;
        if (t >= 0 && t < SEQ) {
          if (lg != curl) {
            curl = lg;
            const u32* vb = &vlds[lg - l_lo][lane * 17];
#pragma unroll
            for (int d = 0; d < 16; ++d) vreg[d] = vb[d];
          }
          float a0 = 0.f, a1 = 0.f, a2 = 0.f, a3 = 0.f;
          if (i < NVR) {
            if (ud2) {
#pragma unroll
              for (int d = 0; d < 16; d += 4) {
                a0 = hwdot2(W[i][d],   vreg[d],   a0);
                a1 = hwdot2(W[i][d+1], vreg[d+1], a1);
                a2 = hwdot2(W[i][d+2], vreg[d+2], a2);
                a3 = hwdot2(W[i][d+3], vreg[d+3], a3);
              }
            } else {
#pragma unroll
              for (int d = 0; d < 16; d += 4) {
                a0 = fmaf(bflo(W[i][d]),   bflo(vreg[d]),   a0);
                a0 = fmaf(bfhi(W[i][d]),   bfhi(vreg[d]),   a0);
                a1 = fmaf(bflo(W[i][d+1]), bflo(vreg[d+1]), a1);
                a1 = fmaf(bfhi(W[i][d+1]), bfhi(vreg[d+1]), a1);
                a2 = fmaf(bflo(W[i][d+2]), bflo(vreg[d+2]), a2);
                a2 = fmaf(bfhi(W[i][d+2]), bfhi(vreg[d+2]), a2);
                a3 = fmaf(bflo(W[i][d+3]), bflo(vreg[d+3]), a3);
                a3 = fmaf(bfhi(W[i][d+3]), bfhi(vreg[d+3]), a3);
              }
            }
          } else {
            const uint4* wl = (const uint4*)&wlds[(wv * NLR + (i - NVR)) * 1024 + lane * 4];
#pragma unroll
            for (int d4 = 0; d4 < 4; ++d4) {
              uint4 w4 = wl[d4 * 64];
              if (ud2) {
                a0 = hwdot2(w4.x, vreg[d4*4+0], a0);
                a1 = hwdot2(w4.y, vreg[d4*4+1], a1);
                a2 = hwdot2(w4.z, vreg[d4*4+2], a2);
                a3 = hwdot2(w4.w, vreg[d4*4+3], a3);
              } else {
                a0 = fmaf(bflo(w4.x), bflo(vreg[d4*4+0]), a0);
                a0 = fmaf(bfhi(w4.x), bfhi(vreg[d4*4+0]), a0);
                a1 = fmaf(bflo(w4.y), bflo(vreg[d4*4+1]), a1);
                a1 = fmaf(bfhi(w4.y), bfhi(vreg[d4*4+1]), a1);
                a2 = fmaf(bflo(w4.z), bflo(vreg[d4*4+2]), a2);
                a2 = fmaf(bfhi(w4.z), bfhi(vreg[d4*4+2]), a2);
                a3 = fmaf(bflo(w4.w), bflo(vreg[d4*4+3]), a3);
                a3 = fmaf(bfhi(w4.w), bfhi(vreg[d4*4+3]), a3);
              }
            }
          }
          float r = (a0 + a1) + (a2 + a3);
          r += __shfl_xor(r, 32);
          r += __shfl_xor(r, 16);
          r += __shfl_xor(r, 8);
          r += __shfl_xor(r, 4);
          r += __shfl_xor(r, 2);
          r += __shfl_xor(r, 1);
          if (lane == 0) zrow[rr] = r;
        }
      }
    }
    __syncthreads();            // C: zrow ready

    // ---- wave0: gates + cell update + publish + flags ----
    if (wv == 0) {
      u16 hb = 0;
      int g = wg * PAIRS + lane;     // valid for lane < PAIRS
      int lg = g >> 10;
      int t = s - lg;
      bool act = (lane < PAIRS) && (t >= 0) && (t < SEQ);
      if (act) {
        float zi = zrow[lane * 4 + 0] + b0;
        float zf = zrow[lane * 4 + 1] + b1g;
        float zg = zrow[lane * 4 + 2] + b2g;
        float zo = zrow[lane * 4 + 3] + b3g;
        float ig = sigm(zi), fg = sigm(zf), gg = tanh_f(zg), og = sigm(zo);
        float c = fg * cst + ig * gg;
        cst = c;
        hb = f2bf(og * tanh_f(c));
      }
      u16 hnb = (u16)__shfl_xor((int)hb, 1);
      if (act && ((lane & 1) == 0)) {
        int j = g & 1023;
        u32 v = (u32)hb | ((u32)hnb << 16);
        agent_store(&slots[(size_t)(lg * RING + (t & 7)) * 512 + (j >> 1)], v);
        if (lg == NL - 1) H5[(size_t)t * 512 + (j >> 1)] = v;
      }
      rel_drain();                               // prior sc1 stores at LLC; no L2 wb/inv
      if (lane == 0) {                           // step s complete: flag = s+2
        agent_store(&flags[l_lo * 64 + (wg - f_lo)], (u32)(s + 2));
        if (l_hi != l_lo) agent_store(&flags[l_hi * 64 + (wg - f_hi)], (u32)(s + 2));
      }
    }
  }
}

// ---------------- K3: out = tanh(leaky_relu(h5) @ w2.T + b2) ----------------
__global__ void __launch_bounds__(256) k_out(const u32* __restrict__ H5,
                                             const void* __restrict__ w2,
                                             const void* __restrict__ b2,
                                             void* __restrict__ out,
                                             const u32* __restrict__ flagp) {
  const u32 isf = *flagp & 1u;
  int t = blockIdx.x, tid = threadIdx.x;
  __shared__ float hs[1024];
  __shared__ float part[256];
#pragma unroll
  for (int r = 0; r < 2; ++r) {
    int idx = tid + r * 256;
    u32 v = H5[(size_t)t * 512 + idx];
    hs[2 * idx]     = lrelu(bflo(v));
    hs[2 * idx + 1] = lrelu(bfhi(v));
  }
  __syncthreads();
  int n = tid & 63, qq = tid >> 6;
  float a = 0.f;
  if (isf) {
    const float* wr = (const float*)w2 + (size_t)n * 1024 + qq * 256;
    const float* hb = &hs[qq * 256];
#pragma unroll
    for (int d = 0; d < 256; ++d) a = fmaf(wr[d], hb[d], a);
  } else {
    const u32* wr = (const u32*)w2 + (size_t)n * 512 + qq * 128;
    const float* hb = &hs[qq * 256];
#pragma unroll
    for (int d = 0; d < 128; ++d) {
      u32 w = wr[d];
      a = fmaf(bflo(w), hb[2 * d], a);
      a = fmaf(bfhi(w), hb[2 * d + 1], a);
    }
  }
  part[tid] = a;
  __syncthreads();
  if (tid < 64) {
    float bb = isf ? ((const float*)b2)[tid] : bf2f(((const u16*)b2)[tid]);
    float y = part[tid] + part[tid + 64] + part[tid + 128] + part[tid + 192] + bb;
    float r = tanh_f(y);
    if (isf) ((float*)out)[(size_t)t * 64 + tid] = r;
    else     ((u16*)out)[(size_t)t * 64 + tid] = f2bf(r);
  }
}

// ---------------- launcher ----------------
extern "C" void kernel_launch(void* const* d_in, const int* in_sizes, int n_in,
                              void* d_out, int out_size, void* d_ws, size_t ws_size,
                              hipStream_t stream) {
  (void)in_sizes; (void)n_in; (void)out_size;
  if (ws_size < WS_NEED) return;

  const void* din = d_in[0];
  const void* w1  = d_in[1];
  const void* b1  = d_in[2];
  const void* Wih = d_in[3];
  const void* Whh = d_in[4];
  const void* bih = d_in[5];
  const void* bhh = d_in[6];
  const void* w2  = d_in[7];
  const void* b2  = d_in[8];
  const void* h0  = d_in[9];
  const void* c0  = d_in[10];

  char* ws = (char*)d_ws;
  u32* X0    = (u32*)(ws + WS_X0);
  u32* H5    = (u32*)(ws + WS_H5);
  u32* slot  = (u32*)(ws + WS_SLOT);
  u32* flags = (u32*)(ws + WS_SYNC);
  u32* dflag = (u32*)(ws + WS_SYNC + 2048);

  hipMemsetAsync(flags, 0, 4096, stream);      // zero flags + dtype word (ws poisoned 0xAA)
  k_detect<<<1, 64, 0, stream>>>((const u32*)w1, dflag);
  k_in  <<<SEQ, 256, 0, stream>>>(din, w1, b1, X0, dflag);
  k_wave<<<NWG, TPB, 0, stream>>>(Wih, Whh, bih, bhh, h0, c0, X0, H5, slot, flags, dflag);
  k_out <<<SEQ, 256, 0, stream>>>(H5, w2, b2, d_out, dflag);
}